// Round 1
// baseline (210.419 us; speedup 1.0000x reference)
//
#include <hip/hip_runtime.h>
#include <math.h>

// ClassMamba collapses: output = [upd_cls, patch(unchanged)].
// upd_cls depends only on token 0 (causal conv + scan from h0=0):
//   q   = cls @ q_w^T
//   xz  = q @ in_proj_w^T ; xi = xz[:1024], z = xz[1024:]
//   xs  = silu(xi * conv_w[:,3] + conv_b)        (only last conv tap at t=0)
//   xd  = xs @ x_proj_w^T ; dtr=xd[:32], Bm=xd[32:48], Cm=xd[48:64]
//   dlt = softplus(dtr @ dt_w^T + dt_b)
//   y   = xs * (dlt * dot(Bm,Cm) + D) ; y *= silu(z)     (A_log unused: h0=0)
//   o   = y @ out_proj_w^T ; upd = o @ proj_w^T + proj_b

#define B_SZ 4
#define DIM 512
#define D_INNER 1024
#define L_TOK 4097
#define TOK_STRIDE (L_TOK * DIM)   // 2,097,664 floats per batch
#define DT_RANK 32
#define D_STATE 16

__device__ __forceinline__ float silu_f(float v) { return v / (1.f + expf(-v)); }

// ---- bulk copy: out[:] = x[:]  (token 0 later overwritten by k_upd) ----
__global__ void k_copy(const float4* __restrict__ x, float4* __restrict__ out, int n4) {
    int i = blockIdx.x * blockDim.x + threadIdx.x;
    if (i < n4) out[i] = x[i];
}

// ---- q[b,d] = dot(x[b,0,:], q_w[d,:])  grid: 8 x 256 ----
__global__ void k_q(const float* __restrict__ x, const float* __restrict__ q_w,
                    float* __restrict__ q_out) {
    __shared__ __align__(16) float cls[DIM];
    int b = blockIdx.x >> 1;
    int d = ((blockIdx.x & 1) << 8) + threadIdx.x;
    const float* xb = x + (size_t)b * TOK_STRIDE;
    for (int k = threadIdx.x; k < DIM; k += 256) cls[k] = xb[k];
    __syncthreads();
    const float4* w = (const float4*)(q_w + (size_t)d * DIM);
    const float4* c = (const float4*)cls;
    float acc = 0.f;
#pragma unroll 8
    for (int k = 0; k < DIM / 4; ++k) {
        float4 wv = w[k], cv = c[k];
        acc += wv.x * cv.x + wv.y * cv.y + wv.z * cv.z + wv.w * cv.w;
    }
    q_out[b * DIM + d] = acc;
}

// ---- xz + conv tap + silu:  grid: 32 x 256 ----
__global__ void k_xz(const float* __restrict__ qv, const float* __restrict__ in_proj_w,
                     const float* __restrict__ conv_w, const float* __restrict__ conv_b,
                     float* __restrict__ xs, float* __restrict__ sz) {
    __shared__ __align__(16) float qs[DIM];
    int b = blockIdx.x >> 3;
    int j = ((blockIdx.x & 7) << 8) + threadIdx.x;  // 0..2047
    for (int k = threadIdx.x; k < DIM; k += 256) qs[k] = qv[b * DIM + k];
    __syncthreads();
    const float4* w = (const float4*)(in_proj_w + (size_t)j * DIM);
    const float4* c = (const float4*)qs;
    float acc = 0.f;
#pragma unroll 8
    for (int k = 0; k < DIM / 4; ++k) {
        float4 wv = w[k], cv = c[k];
        acc += wv.x * cv.x + wv.y * cv.y + wv.z * cv.z + wv.w * cv.w;
    }
    if (j < D_INNER) {
        float v = acc * conv_w[j * 4 + 3] + conv_b[j];
        xs[b * D_INNER + j] = silu_f(v);
    } else {
        sz[b * D_INNER + (j - D_INNER)] = silu_f(acc);
    }
}

// ---- x_dbl + softplus(delta) + scan@t0 + gate:  grid: 8 x 512 ----
__global__ void k_y(const float* __restrict__ xs, const float* __restrict__ sz,
                    const float* __restrict__ x_proj_w, const float* __restrict__ dt_w,
                    const float* __restrict__ dt_b, const float* __restrict__ Dp,
                    float* __restrict__ yy) {
    __shared__ float part[64][9];
    __shared__ float xd[64];
    int b = blockIdx.x >> 1;
    int d = ((blockIdx.x & 1) << 9) + threadIdx.x;  // 0..1023
    const float* xsb = xs + b * D_INNER;

    // stage A: x_dbl[r] partials (8 threads per row r)
    int r = threadIdx.x >> 3;
    int p = threadIdx.x & 7;
    const float4* w = (const float4*)(x_proj_w + r * D_INNER + p * 128);
    const float4* v = (const float4*)(xsb + p * 128);
    float acc = 0.f;
#pragma unroll 8
    for (int k = 0; k < 32; ++k) {
        float4 wv = w[k], cv = v[k];
        acc += wv.x * cv.x + wv.y * cv.y + wv.z * cv.z + wv.w * cv.w;
    }
    part[r][p] = acc;
    __syncthreads();
    if (threadIdx.x < 64) {
        float s = 0.f;
#pragma unroll
        for (int q = 0; q < 8; ++q) s += part[threadIdx.x][q];
        xd[threadIdx.x] = s;
    }
    __syncthreads();

    // stage B: per-d epilogue (xd broadcast reads from LDS)
    float S = 0.f;
#pragma unroll
    for (int n = 0; n < D_STATE; ++n) S += xd[32 + n] * xd[48 + n];
    float dp = dt_b[d];
    const float* dw = dt_w + d * DT_RANK;
#pragma unroll
    for (int rr = 0; rr < DT_RANK; ++rr) dp += xd[rr] * dw[rr];
    float delta = (dp > 20.f) ? dp : log1pf(expf(dp));
    float u = xsb[d];
    float yv = u * (delta * S + Dp[d]);
    yy[b * D_INNER + d] = yv * sz[b * D_INNER + d];
}

// ---- o[b,i] = dot(yy[b,:], out_proj_w[i,:])  grid: 8 x 256 ----
__global__ void k_out(const float* __restrict__ yy, const float* __restrict__ out_proj_w,
                      float* __restrict__ o) {
    __shared__ __align__(16) float ys[D_INNER];
    int b = blockIdx.x >> 1;
    int i = ((blockIdx.x & 1) << 8) + threadIdx.x;
    for (int k = threadIdx.x; k < D_INNER; k += 256) ys[k] = yy[b * D_INNER + k];
    __syncthreads();
    const float4* w = (const float4*)(out_proj_w + (size_t)i * D_INNER);
    const float4* c = (const float4*)ys;
    float acc = 0.f;
#pragma unroll 8
    for (int k = 0; k < D_INNER / 4; ++k) {
        float4 wv = w[k], cv = c[k];
        acc += wv.x * cv.x + wv.y * cv.y + wv.z * cv.z + wv.w * cv.w;
    }
    o[b * DIM + i] = acc;
}

// ---- upd[b,j] = dot(o[b,:], proj_w[j,:]) + proj_b[j] -> out token 0  grid: 8 x 256 ----
__global__ void k_upd(const float* __restrict__ o, const float* __restrict__ proj_w,
                      const float* __restrict__ proj_b, float* __restrict__ out) {
    __shared__ __align__(16) float os[DIM];
    int b = blockIdx.x >> 1;
    int j = ((blockIdx.x & 1) << 8) + threadIdx.x;
    for (int k = threadIdx.x; k < DIM; k += 256) os[k] = o[b * DIM + k];
    __syncthreads();
    const float4* w = (const float4*)(proj_w + (size_t)j * DIM);
    const float4* c = (const float4*)os;
    float acc = proj_b[j];
#pragma unroll 8
    for (int k = 0; k < DIM / 4; ++k) {
        float4 wv = w[k], cv = c[k];
        acc += wv.x * cv.x + wv.y * cv.y + wv.z * cv.z + wv.w * cv.w;
    }
    out[(size_t)b * TOK_STRIDE + j] = acc;
}

extern "C" void kernel_launch(void* const* d_in, const int* in_sizes, int n_in,
                              void* d_out, int out_size, void* d_ws, size_t ws_size,
                              hipStream_t stream) {
    const float* x          = (const float*)d_in[0];
    const float* q_w        = (const float*)d_in[1];
    const float* in_proj_w  = (const float*)d_in[2];
    const float* conv_w     = (const float*)d_in[3];
    const float* conv_b     = (const float*)d_in[4];
    const float* x_proj_w   = (const float*)d_in[5];
    const float* dt_w       = (const float*)d_in[6];
    const float* dt_b       = (const float*)d_in[7];
    // d_in[8] = A_log: unused (h0 = 0 -> dA multiplies zero state)
    const float* Dp         = (const float*)d_in[9];
    const float* out_proj_w = (const float*)d_in[10];
    const float* proj_w     = (const float*)d_in[11];
    const float* proj_b     = (const float*)d_in[12];
    float* out = (float*)d_out;
    float* ws  = (float*)d_ws;

    float* q_ws  = ws;          // 2048 floats
    float* xs_ws = ws + 2048;   // 4096
    float* sz_ws = ws + 6144;   // 4096
    float* yy_ws = ws + 10240;  // 4096
    float* o_ws  = ws + 14336;  // 2048

    int n4 = (B_SZ * TOK_STRIDE) / 4;  // 2,097,664 float4s
    k_copy<<<(n4 + 255) / 256, 256, 0, stream>>>((const float4*)x, (float4*)out, n4);
    k_q  <<<8,  256, 0, stream>>>(x, q_w, q_ws);
    k_xz <<<32, 256, 0, stream>>>(q_ws, in_proj_w, conv_w, conv_b, xs_ws, sz_ws);
    k_y  <<<8,  512, 0, stream>>>(xs_ws, sz_ws, x_proj_w, dt_w, dt_b, Dp, yy_ws);
    k_out<<<8,  256, 0, stream>>>(yy_ws, out_proj_w, o_ws);
    k_upd<<<8,  256, 0, stream>>>(o_ws, proj_w, proj_b, out);
}